// Round 1
// baseline (404.260 us; speedup 1.0000x reference)
//
#include <hip/hip_runtime.h>
#include <math.h>

#define NEG 0.2f
#define LNEPS 1e-5f

__device__ __forceinline__ float lrelu(float x){ return x > 0.f ? x : NEG*x; }

// -------- GEMM: C[M,256] = A[M,256] * B[256,256], f32, 64x64 tile --------
__global__ __launch_bounds__(256) void gemm_k(const float* __restrict__ A,
                                              const float* __restrict__ B,
                                              float* __restrict__ C, int M){
  const int BM=64, BK=16;
  __shared__ float As[BK][BM+1];
  __shared__ float Bs[BK][64];
  int t = threadIdx.x;
  int tx = t & 15, ty = t >> 4;
  int rb = blockIdx.y * BM;
  int cb = blockIdx.x * 64;
  float acc[4][4] = {};
  for (int kb = 0; kb < 256; kb += BK) {
    { // A tile 64x16, each thread 4 contiguous k
      int l = t*4;
      int r = l >> 4;
      int k = l & 15;
      float4 v = {0.f,0.f,0.f,0.f};
      int row = rb + r;
      if (row < M) v = *(const float4*)(A + (size_t)row*256 + kb + k);
      As[k+0][r]=v.x; As[k+1][r]=v.y; As[k+2][r]=v.z; As[k+3][r]=v.w;
    }
    { // B tile 16x64
      int l = t*4;
      int k = l >> 6;
      int c = l & 63;
      float4 v = *(const float4*)(B + (size_t)(kb+k)*256 + cb + c);
      *(float4*)(&Bs[k][c]) = v;
    }
    __syncthreads();
    #pragma unroll
    for (int k=0;k<BK;k++){
      float a[4], b[4];
      #pragma unroll
      for (int i=0;i<4;i++) a[i]=As[k][ty*4+i];
      #pragma unroll
      for (int j=0;j<4;j++) b[j]=Bs[k][tx*4+j];
      #pragma unroll
      for (int i=0;i<4;i++)
        #pragma unroll
        for (int j=0;j<4;j++)
          acc[i][j] += a[i]*b[j];
    }
    __syncthreads();
  }
  #pragma unroll
  for (int i=0;i<4;i++){
    int row = rb + ty*4 + i;
    if (row < M){
      float4 v = {acc[i][0],acc[i][1],acc[i][2],acc[i][3]};
      *(float4*)(C + (size_t)row*256 + cb + tx*4) = v;
    }
  }
}

// -------- per-node attention half-logits: one wave per node --------
__global__ __launch_bounds__(256) void att_k(const float* __restrict__ xl,
                                             const float* __restrict__ att_src,
                                             const float* __restrict__ att_dst,
                                             float* __restrict__ a_src,
                                             float* __restrict__ a_dst, int n){
  int gt = blockIdx.x*blockDim.x + threadIdx.x;
  int node = gt >> 6;
  int lane = threadIdx.x & 63;
  if (node >= n) return;
  float4 v  = *(const float4*)(xl + (size_t)node*256 + lane*4);
  float4 as = *(const float4*)(att_src + lane*4);
  float4 ad = *(const float4*)(att_dst + lane*4);
  float ps = v.x*as.x + v.y*as.y + v.z*as.z + v.w*as.w;
  float pd = v.x*ad.x + v.y*ad.y + v.z*ad.z + v.w*ad.w;
  ps += __shfl_xor(ps,1); pd += __shfl_xor(pd,1);
  ps += __shfl_xor(ps,2); pd += __shfl_xor(pd,2);
  ps += __shfl_xor(ps,4); pd += __shfl_xor(pd,4);
  if ((lane&7)==0){ int h=lane>>3; a_src[(size_t)node*8+h]=ps; a_dst[(size_t)node*8+h]=pd; }
}

// -------- CSR build --------
__global__ void deg_k(const int* __restrict__ dst, int* __restrict__ deg, int E){
  int e = blockIdx.x*blockDim.x+threadIdx.x;
  if (e<E) atomicAdd(&deg[dst[e]],1);
}

__global__ __launch_bounds__(1024) void scan_k(const int* __restrict__ deg,
                                               int* __restrict__ off, int n){
  __shared__ int wsum[16];
  __shared__ int carry_s;
  int tid=threadIdx.x, lane=tid&63, wid=tid>>6;
  if (tid==0) carry_s=0;
  __syncthreads();
  for (int base=0; base<n; base+=1024){
    int i=base+tid;
    int v = (i<n)?deg[i]:0;
    int x=v;
    #pragma unroll
    for (int s=1;s<64;s<<=1){ int t2=__shfl_up(x,s); if (lane>=s) x+=t2; }
    if (lane==63) wsum[wid]=x;
    __syncthreads();
    if (tid<16){
      int y=wsum[tid];
      #pragma unroll
      for (int s=1;s<16;s<<=1){ int t2=__shfl_up(y,s); if (tid>=s) y+=t2; }
      wsum[tid]=y;
    }
    __syncthreads();
    int prefix=(wid? wsum[wid-1]:0)+carry_s;
    if (i<n) off[i]=prefix + x - v;
    int total=wsum[15]+carry_s;
    __syncthreads();
    if (tid==0) carry_s=total;
    __syncthreads();
  }
  if (threadIdx.x==0) off[n]=carry_s;
}

__global__ void scatter_k(const int* __restrict__ src, const int* __restrict__ dst,
                          const int* __restrict__ off, int* __restrict__ cur,
                          int* __restrict__ sorted, int E){
  int e=blockIdx.x*blockDim.x+threadIdx.x;
  if (e<E){
    int d=dst[e];
    int pos=off[d]+atomicAdd(&cur[d],1);
    sorted[pos]=src[e];
  }
}

// -------- fused aggregate + softmax + LayerNorm: one wave per dst node --------
__global__ __launch_bounds__(256) void agg_k(const float* __restrict__ xl,
    const float* __restrict__ a_src, const float* __restrict__ a_dst,
    const int* __restrict__ off, const int* __restrict__ sorted,
    const float* __restrict__ bias, const float* __restrict__ gamma,
    const float* __restrict__ beta, float* __restrict__ out, int n){
  int node = blockIdx.x*4 + (threadIdx.x>>6);
  int lane = threadIdx.x & 63;
  if (node >= n) return;
  int h = lane >> 3;
  float adst[8];
  #pragma unroll
  for (int q=0;q<8;q++) adst[q]=a_dst[(size_t)node*8+q];
  int s0=off[node], d=off[node+1]-s0;

  // pass A1: per-head max over all in-edges (incl. self loop)
  float m[8];
  #pragma unroll
  for (int q=0;q<8;q++) m[q] = lrelu(a_src[(size_t)node*8+q]+adst[q]);
  for (int i=lane;i<d;i+=64){
    int s=sorted[s0+i];
    #pragma unroll
    for (int q=0;q<8;q++){
      float lg=lrelu(a_src[(size_t)s*8+q]+adst[q]);
      m[q]=fmaxf(m[q],lg);
    }
  }
  #pragma unroll
  for (int q=0;q<8;q++){
    #pragma unroll
    for (int s=1;s<64;s<<=1) m[q]=fmaxf(m[q], __shfl_xor(m[q],s));
  }

  // pass A2: per-head denom
  float den[8];
  #pragma unroll
  for (int q=0;q<8;q++) den[q] = (lane==0)? __expf(lrelu(a_src[(size_t)node*8+q]+adst[q]) - m[q]) : 0.f;
  for (int i=lane;i<d;i+=64){
    int s=sorted[s0+i];
    #pragma unroll
    for (int q=0;q<8;q++) den[q] += __expf(lrelu(a_src[(size_t)s*8+q]+adst[q]) - m[q]);
  }
  #pragma unroll
  for (int q=0;q<8;q++){
    #pragma unroll
    for (int s=1;s<64;s<<=1) den[q] += __shfl_xor(den[q],s);
  }

  // pass B: weighted gather of xl[src]; lane covers features lane*4..lane*4+3 (head h)
  float mh = m[h];
  float rd = 1.0f/den[h];
  float myadst = adst[h];
  float4 acc;
  { // self loop
    float al = __expf(lrelu(a_src[(size_t)node*8+h]+myadst)-mh)*rd;
    float4 v = *(const float4*)(xl + (size_t)node*256 + lane*4);
    acc.x = al*v.x; acc.y=al*v.y; acc.z=al*v.z; acc.w=al*v.w;
  }
  for (int i=0;i<d;i++){
    int s = sorted[s0+i];
    float al = __expf(lrelu(a_src[(size_t)s*8+h]+myadst)-mh)*rd;
    float4 v = *(const float4*)(xl + (size_t)s*256 + lane*4);
    acc.x += al*v.x; acc.y += al*v.y; acc.z += al*v.z; acc.w += al*v.w;
  }

  // LayerNorm epilogue over 256 features (cross-wave reduce)
  float4 b4 = *(const float4*)(bias + lane*4);
  float4 o = {acc.x+b4.x, acc.y+b4.y, acc.z+b4.z, acc.w+b4.w};
  float sum = o.x+o.y+o.z+o.w;
  float ssq = o.x*o.x+o.y*o.y+o.z*o.z+o.w*o.w;
  #pragma unroll
  for (int s=1;s<64;s<<=1){ sum += __shfl_xor(sum,s); ssq += __shfl_xor(ssq,s); }
  float mean = sum*(1.0f/256.0f);
  float var  = ssq*(1.0f/256.0f) - mean*mean;
  float rstd = rsqrtf(var + LNEPS);
  float4 g  = *(const float4*)(gamma + lane*4);
  float4 be = *(const float4*)(beta + lane*4);
  o.x = (o.x-mean)*rstd*g.x+be.x;
  o.y = (o.y-mean)*rstd*g.y+be.y;
  o.z = (o.z-mean)*rstd*g.z+be.z;
  o.w = (o.w-mean)*rstd*g.w+be.w;
  *(float4*)(out + (size_t)node*256 + lane*4) = o;
}

extern "C" void kernel_launch(void* const* d_in, const int* in_sizes, int n_in,
                              void* d_out, int out_size, void* d_ws, size_t ws_size,
                              hipStream_t stream){
  const float* x       = (const float*)d_in[0];
  const int*   ei      = (const int*)  d_in[1];
  const float* W       = (const float*)d_in[2];
  const float* att_src = (const float*)d_in[3];
  const float* att_dst = (const float*)d_in[4];
  const float* bias    = (const float*)d_in[5];
  const float* gamma   = (const float*)d_in[6];
  const float* beta    = (const float*)d_in[7];
  float* out = (float*)d_out;

  int N = in_sizes[0]/256;
  int E = in_sizes[1]/2;
  const int* srcp = ei;
  const int* dstp = ei + E;

  float* xl    = (float*)d_ws;
  float* a_src = xl + (size_t)N*256;
  float* a_dst = a_src + (size_t)N*8;
  int*   deg   = (int*)(a_dst + (size_t)N*8);
  int*   off   = deg + N;
  int*   cur   = off + N + 1;
  int*   sorted= cur + N;

  hipMemsetAsync(deg, 0, (size_t)N*sizeof(int), stream);
  hipMemsetAsync(cur, 0, (size_t)N*sizeof(int), stream);

  dim3 gg(4, (N+63)/64);
  gemm_k<<<gg, 256, 0, stream>>>(x, W, xl, N);
  att_k<<<(N*64+255)/256, 256, 0, stream>>>(xl, att_src, att_dst, a_src, a_dst, N);
  deg_k<<<(E+255)/256, 256, 0, stream>>>(dstp, deg, E);
  scan_k<<<1, 1024, 0, stream>>>(deg, off, N);
  scatter_k<<<(E+255)/256, 256, 0, stream>>>(srcp, dstp, off, cur, sorted, E);
  agg_k<<<(N+3)/4, 256, 0, stream>>>(xl, a_src, a_dst, off, sorted, bias, gamma, beta, out, N);
}

// Round 2
// 307.243 us; speedup vs baseline: 1.3158x; 1.3158x over previous
//
#include <hip/hip_runtime.h>
#include <math.h>

#define NEG 0.2f
#define LNEPS 1e-5f

typedef __attribute__((ext_vector_type(8))) short bf16x8;
typedef __attribute__((ext_vector_type(4))) float f32x4;

__device__ __forceinline__ float lrelu(float x){ return x > 0.f ? x : NEG*x; }

// f32 -> bf16 (round to nearest even), as raw short
__device__ __forceinline__ short f2b(float f){
  unsigned u = __float_as_uint(f);
  unsigned r = u + 0x7fffu + ((u >> 16) & 1u);
  return (short)(r >> 16);
}

// -------- W transpose + bf16 convert: WT[c][k] = bf16(W[k][c]) --------
__global__ __launch_bounds__(256) void wt_k(const float* __restrict__ W,
                                            unsigned short* __restrict__ WT){
  int idx = blockIdx.x*256 + threadIdx.x;   // 65536 elements
  int k = idx >> 8, c = idx & 255;
  WT[c*256 + k] = (unsigned short)f2b(W[idx]);
}

// -------- MFMA GEMM: C[M,256] = A[M,256] * W, B given as WT bf16 --------
// LDS-free: W^T is L2-resident (128 KB); A rows have no intra-block reuse.
// Wave w of block b owns rows b*64 + w*16 .. +15, all 256 cols.
__global__ __launch_bounds__(256) void mfma_gemm_k(const float* __restrict__ A,
    const unsigned short* __restrict__ WT, float* __restrict__ C, int M){
  int w    = threadIdx.x >> 6;
  int l    = threadIdx.x & 63;
  int l15  = l & 15;
  int kg   = l >> 4;               // k-group 0..3
  int r16  = blockIdx.x*64 + w*16; // wave row base
  int row  = r16 + l15;            // A-frag row for this lane
  int arow = row < M ? row : (M-1);

  f32x4 acc[16];
  #pragma unroll
  for (int i=0;i<16;i++) acc[i] = (f32x4){0.f,0.f,0.f,0.f};

  for (int kk=0; kk<256; kk+=32){
    const float* ap = A + (size_t)arow*256 + kk + kg*8;
    float4 a0 = *(const float4*)ap;
    float4 a1 = *(const float4*)(ap+4);
    bf16x8 af;
    af[0]=f2b(a0.x); af[1]=f2b(a0.y); af[2]=f2b(a0.z); af[3]=f2b(a0.w);
    af[4]=f2b(a1.x); af[5]=f2b(a1.y); af[6]=f2b(a1.z); af[7]=f2b(a1.w);
    #pragma unroll
    for (int ct=0; ct<16; ct++){
      int col = ct*16 + l15;
      bf16x8 bf = *(const bf16x8*)(WT + (size_t)col*256 + kk + kg*8);
      acc[ct] = __builtin_amdgcn_mfma_f32_16x16x32_bf16(af, bf, acc[ct], 0, 0, 0);
    }
  }
  // D layout: col = l&15, row = (l>>4)*4 + reg
  int orow_base = r16 + kg*4;
  #pragma unroll
  for (int ct=0; ct<16; ct++){
    #pragma unroll
    for (int rr=0; rr<4; rr++){
      int orow = orow_base + rr;
      if (orow < M) C[(size_t)orow*256 + ct*16 + l15] = acc[ct][rr];
    }
  }
}

// -------- per-node attention half-logits: one wave per node --------
__global__ __launch_bounds__(256) void att_k(const float* __restrict__ xl,
                                             const float* __restrict__ att_src,
                                             const float* __restrict__ att_dst,
                                             float* __restrict__ a_src,
                                             float* __restrict__ a_dst, int n){
  int gt = blockIdx.x*blockDim.x + threadIdx.x;
  int node = gt >> 6;
  int lane = threadIdx.x & 63;
  if (node >= n) return;
  float4 v  = *(const float4*)(xl + (size_t)node*256 + lane*4);
  float4 as = *(const float4*)(att_src + lane*4);
  float4 ad = *(const float4*)(att_dst + lane*4);
  float ps = v.x*as.x + v.y*as.y + v.z*as.z + v.w*as.w;
  float pd = v.x*ad.x + v.y*ad.y + v.z*ad.z + v.w*ad.w;
  ps += __shfl_xor(ps,1); pd += __shfl_xor(pd,1);
  ps += __shfl_xor(ps,2); pd += __shfl_xor(pd,2);
  ps += __shfl_xor(ps,4); pd += __shfl_xor(pd,4);
  if ((lane&7)==0){ int h=lane>>3; a_src[(size_t)node*8+h]=ps; a_dst[(size_t)node*8+h]=pd; }
}

// -------- CSR build --------
__global__ void deg_k(const int* __restrict__ dst, int* __restrict__ deg, int E){
  int e = blockIdx.x*blockDim.x+threadIdx.x;
  if (e<E) atomicAdd(&deg[dst[e]],1);
}

// block-local exclusive scan of 1024 elements, block sum out
__global__ __launch_bounds__(1024) void scan1_k(const int* __restrict__ deg,
                                                int* __restrict__ off,
                                                int* __restrict__ bsum, int n){
  __shared__ int wsum[16];
  int tid=threadIdx.x, lane=tid&63, wid=tid>>6;
  int i = blockIdx.x*1024 + tid;
  int v = (i<n)?deg[i]:0;
  int x = v;
  #pragma unroll
  for (int s=1;s<64;s<<=1){ int t2=__shfl_up(x,s); if (lane>=s) x+=t2; }
  if (lane==63) wsum[wid]=x;
  __syncthreads();
  if (tid<16){
    int y=wsum[tid];
    #pragma unroll
    for (int s=1;s<16;s<<=1){ int t2=__shfl_up(y,s); if (tid>=s) y+=t2; }
    wsum[tid]=y;
  }
  __syncthreads();
  int prefix=(wid? wsum[wid-1]:0);
  if (i<n) off[i]=prefix + x - v;
  if (tid==0) bsum[blockIdx.x]=wsum[15];
}

// exclusive scan of up to 64 block sums (single wave)
__global__ void scan2_k(int* __restrict__ bsum, int nb, int* __restrict__ offn){
  int lane = threadIdx.x;
  int v = (lane<nb)?bsum[lane]:0;
  int x = v;
  #pragma unroll
  for (int s=1;s<64;s<<=1){ int t2=__shfl_up(x,s); if (lane>=s) x+=t2; }
  if (lane<nb) bsum[lane] = x - v;
  if (lane==63) *offn = x;
}

__global__ __launch_bounds__(1024) void scan3_k(int* __restrict__ off,
                                                const int* __restrict__ bsum, int n){
  int i = blockIdx.x*1024 + threadIdx.x;
  if (i<n) off[i] += bsum[blockIdx.x];
}

__global__ void scatter_k(const int* __restrict__ src, const int* __restrict__ dst,
                          const int* __restrict__ off, int* __restrict__ cur,
                          int* __restrict__ sorted, int E){
  int e=blockIdx.x*blockDim.x+threadIdx.x;
  if (e<E){
    int d=dst[e];
    int pos=off[d]+atomicAdd(&cur[d],1);
    sorted[pos]=src[e];
  }
}

// -------- fused single-pass aggregate + softmax + LayerNorm --------
// alpha = exp(l)/sum(exp(l)) without seg-max: logits are O(+-4), exp is safe.
// den is identical on all 8 lanes of a head -> no cross-lane reduce needed.
__global__ __launch_bounds__(256) void agg2_k(const float* __restrict__ xl,
    const float* __restrict__ a_src, const float* __restrict__ a_dst,
    const int* __restrict__ off, const int* __restrict__ sorted,
    const float* __restrict__ bias, const float* __restrict__ gamma,
    const float* __restrict__ beta, float* __restrict__ out, int n){
  int node = blockIdx.x*4 + (threadIdx.x>>6);
  int lane = threadIdx.x & 63;
  if (node >= n) return;
  int h = lane >> 3;
  float myadst = a_dst[(size_t)node*8+h];
  int s0=off[node], d=off[node+1]-s0;

  // self loop
  float wgt = __expf(lrelu(a_src[(size_t)node*8+h]+myadst));
  float den = wgt;
  float4 v0 = *(const float4*)(xl + (size_t)node*256 + lane*4);
  float ax=wgt*v0.x, ay=wgt*v0.y, az=wgt*v0.z, aw=wgt*v0.w;

  int i=0;
  for (; i+2<=d; i+=2){
    int s1 = sorted[s0+i];
    int s2 = sorted[s0+i+1];
    float w1 = __expf(lrelu(a_src[(size_t)s1*8+h]+myadst));
    float w2 = __expf(lrelu(a_src[(size_t)s2*8+h]+myadst));
    float4 v1 = *(const float4*)(xl + (size_t)s1*256 + lane*4);
    float4 v2 = *(const float4*)(xl + (size_t)s2*256 + lane*4);
    den += w1 + w2;
    ax += w1*v1.x + w2*v2.x;
    ay += w1*v1.y + w2*v2.y;
    az += w1*v1.z + w2*v2.z;
    aw += w1*v1.w + w2*v2.w;
  }
  if (i<d){
    int s1 = sorted[s0+i];
    float w1 = __expf(lrelu(a_src[(size_t)s1*8+h]+myadst));
    float4 v1 = *(const float4*)(xl + (size_t)s1*256 + lane*4);
    den += w1;
    ax += w1*v1.x; ay += w1*v1.y; az += w1*v1.z; aw += w1*v1.w;
  }

  float rd = 1.0f/den;
  float4 b4 = *(const float4*)(bias + lane*4);
  float4 o = {ax*rd+b4.x, ay*rd+b4.y, az*rd+b4.z, aw*rd+b4.w};

  // LayerNorm over 256 features (cross-wave reduce)
  float sum = o.x+o.y+o.z+o.w;
  float ssq = o.x*o.x+o.y*o.y+o.z*o.z+o.w*o.w;
  #pragma unroll
  for (int s=1;s<64;s<<=1){ sum += __shfl_xor(sum,s); ssq += __shfl_xor(ssq,s); }
  float mean = sum*(1.0f/256.0f);
  float var  = ssq*(1.0f/256.0f) - mean*mean;
  float rstd = rsqrtf(var + LNEPS);
  float4 g  = *(const float4*)(gamma + lane*4);
  float4 be = *(const float4*)(beta + lane*4);
  o.x = (o.x-mean)*rstd*g.x+be.x;
  o.y = (o.y-mean)*rstd*g.y+be.y;
  o.z = (o.z-mean)*rstd*g.z+be.z;
  o.w = (o.w-mean)*rstd*g.w+be.w;
  *(float4*)(out + (size_t)node*256 + lane*4) = o;
}

extern "C" void kernel_launch(void* const* d_in, const int* in_sizes, int n_in,
                              void* d_out, int out_size, void* d_ws, size_t ws_size,
                              hipStream_t stream){
  const float* x       = (const float*)d_in[0];
  const int*   ei      = (const int*)  d_in[1];
  const float* W       = (const float*)d_in[2];
  const float* att_src = (const float*)d_in[3];
  const float* att_dst = (const float*)d_in[4];
  const float* bias    = (const float*)d_in[5];
  const float* gamma   = (const float*)d_in[6];
  const float* beta    = (const float*)d_in[7];
  float* out = (float*)d_out;

  int N = in_sizes[0]/256;
  int E = in_sizes[1]/2;
  const int* srcp = ei;
  const int* dstp = ei + E;

  float* xl    = (float*)d_ws;
  float* a_src = xl + (size_t)N*256;
  float* a_dst = a_src + (size_t)N*8;
  int*   deg   = (int*)(a_dst + (size_t)N*8);
  int*   off   = deg + N;
  int*   cur   = off + N + 1;
  int*   sorted= cur + N;
  int*   bsum  = sorted + E;
  unsigned short* WT = (unsigned short*)(bsum + 1024);

  hipMemsetAsync(deg, 0, (size_t)N*sizeof(int), stream);
  hipMemsetAsync(cur, 0, (size_t)N*sizeof(int), stream);

  int nb = (N + 1023)/1024;

  wt_k<<<256, 256, 0, stream>>>(W, WT);
  mfma_gemm_k<<<(N+63)/64, 256, 0, stream>>>(x, WT, xl, N);
  att_k<<<(N*64+255)/256, 256, 0, stream>>>(xl, att_src, att_dst, a_src, a_dst, N);
  deg_k<<<(E+255)/256, 256, 0, stream>>>(dstp, deg, E);
  scan1_k<<<nb, 1024, 0, stream>>>(deg, off, bsum, N);
  scan2_k<<<1, 64, 0, stream>>>(bsum, nb, off + N);
  scan3_k<<<nb, 1024, 0, stream>>>(off, bsum, N);
  scatter_k<<<(E+255)/256, 256, 0, stream>>>(srcp, dstp, off, cur, sorted, E);
  agg2_k<<<(N+3)/4, 256, 0, stream>>>(xl, a_src, a_dst, off, sorted, bias, gamma, beta, out, N);
}

// Round 3
// 257.683 us; speedup vs baseline: 1.5688x; 1.1923x over previous
//
#include <hip/hip_runtime.h>
#include <math.h>

#define NEG 0.2f
#define LNEPS 1e-5f

typedef __attribute__((ext_vector_type(8))) short bf16x8;
typedef __attribute__((ext_vector_type(4))) float f32x4;

__device__ __forceinline__ float lrelu(float x){ return x > 0.f ? x : NEG*x; }

// f32 -> bf16 (round to nearest even), as raw short
__device__ __forceinline__ short f2b(float f){
  unsigned u = __float_as_uint(f);
  unsigned r = u + 0x7fffu + ((u >> 16) & 1u);
  return (short)(r >> 16);
}
__device__ __forceinline__ float b2f(unsigned short u){
  return __uint_as_float(((unsigned)u) << 16);
}

// -------- W transpose + bf16 convert: WT[c][k] = bf16(W[k][c]) --------
__global__ __launch_bounds__(256) void wt_k(const float* __restrict__ W,
                                            unsigned short* __restrict__ WT){
  int idx = blockIdx.x*256 + threadIdx.x;   // 65536 elements
  int k = idx >> 8, c = idx & 255;
  WT[c*256 + k] = (unsigned short)f2b(W[idx]);
}

// -------- MFMA GEMM + fused att half-logits --------
// C_b[M,256] (bf16) = A[M,256] * W;  a_src/a_dst[M,8] from acc in-register.
// Wave w of block b owns rows b*64 + w*16 .. +15, all 256 cols.
__global__ __launch_bounds__(256) void mfma_gemm_k(const float* __restrict__ A,
    const unsigned short* __restrict__ WT, unsigned short* __restrict__ Cb,
    const float* __restrict__ att_src, const float* __restrict__ att_dst,
    float* __restrict__ a_src, float* __restrict__ a_dst, int M){
  int w    = threadIdx.x >> 6;
  int l    = threadIdx.x & 63;
  int l15  = l & 15;
  int kg   = l >> 4;               // k-group 0..3
  int r16  = blockIdx.x*64 + w*16; // wave row base
  int row  = r16 + l15;            // A-frag row for this lane
  int arow = row < M ? row : (M-1);

  f32x4 acc[16];
  #pragma unroll
  for (int i=0;i<16;i++) acc[i] = (f32x4){0.f,0.f,0.f,0.f};

  for (int kk=0; kk<256; kk+=32){
    const float* ap = A + (size_t)arow*256 + kk + kg*8;
    float4 a0 = *(const float4*)ap;
    float4 a1 = *(const float4*)(ap+4);
    bf16x8 af;
    af[0]=f2b(a0.x); af[1]=f2b(a0.y); af[2]=f2b(a0.z); af[3]=f2b(a0.w);
    af[4]=f2b(a1.x); af[5]=f2b(a1.y); af[6]=f2b(a1.z); af[7]=f2b(a1.w);
    #pragma unroll
    for (int ct=0; ct<16; ct++){
      int col = ct*16 + l15;
      bf16x8 bf = *(const bf16x8*)(WT + (size_t)col*256 + kk + kg*8);
      acc[ct] = __builtin_amdgcn_mfma_f32_16x16x32_bf16(af, bf, acc[ct], 0, 0, 0);
    }
  }

  // D layout: col = l&15, row = (l>>4)*4 + reg
  int orow_base = r16 + kg*4;

  // store bf16 xl
  #pragma unroll
  for (int ct=0; ct<16; ct++){
    #pragma unroll
    for (int rr=0; rr<4; rr++){
      int orow = orow_base + rr;
      if (orow < M) Cb[(size_t)orow*256 + ct*16 + l15] = (unsigned short)f2b(acc[ct][rr]);
    }
  }

  // fused attention half-logits: per row, per head h, dot over cols of head h.
  // col = ct*16+l15; head(col) = col>>5 -> ct in {2h, 2h+1}.
  float as_r[16], ad_r[16];
  #pragma unroll
  for (int ct=0;ct<16;ct++){
    as_r[ct] = att_src[ct*16 + l15];
    ad_r[ct] = att_dst[ct*16 + l15];
  }
  #pragma unroll
  for (int rr=0; rr<4; rr++){
    int orow = orow_base + rr;
    #pragma unroll
    for (int h=0; h<8; h++){
      float ps = acc[2*h][rr]*as_r[2*h] + acc[2*h+1][rr]*as_r[2*h+1];
      float pd = acc[2*h][rr]*ad_r[2*h] + acc[2*h+1][rr]*ad_r[2*h+1];
      ps += __shfl_xor(ps,1); pd += __shfl_xor(pd,1);
      ps += __shfl_xor(ps,2); pd += __shfl_xor(pd,2);
      ps += __shfl_xor(ps,4); pd += __shfl_xor(pd,4);
      ps += __shfl_xor(ps,8); pd += __shfl_xor(pd,8);
      if (l15==0 && orow < M){
        a_src[(size_t)orow*8+h] = ps;
        a_dst[(size_t)orow*8+h] = pd;
      }
    }
  }
}

// -------- CSR build --------
__global__ void deg_k(const int* __restrict__ dst, int* __restrict__ deg, int E){
  int e = blockIdx.x*blockDim.x+threadIdx.x;
  if (e<E) atomicAdd(&deg[dst[e]],1);
}

// block-local exclusive scan of 1024 elements, block sum out
__global__ __launch_bounds__(1024) void scan1_k(const int* __restrict__ deg,
                                                int* __restrict__ off,
                                                int* __restrict__ bsum, int n){
  __shared__ int wsum[16];
  int tid=threadIdx.x, lane=tid&63, wid=tid>>6;
  int i = blockIdx.x*1024 + tid;
  int v = (i<n)?deg[i]:0;
  int x = v;
  #pragma unroll
  for (int s=1;s<64;s<<=1){ int t2=__shfl_up(x,s); if (lane>=s) x+=t2; }
  if (lane==63) wsum[wid]=x;
  __syncthreads();
  if (tid<16){
    int y=wsum[tid];
    #pragma unroll
    for (int s=1;s<16;s<<=1){ int t2=__shfl_up(y,s); if (tid>=s) y+=t2; }
    wsum[tid]=y;
  }
  __syncthreads();
  int prefix=(wid? wsum[wid-1]:0);
  if (i<n) off[i]=prefix + x - v;
  if (tid==0) bsum[blockIdx.x]=wsum[15];
}

// exclusive scan of up to 64 block sums (single wave)
__global__ void scan2_k(int* __restrict__ bsum, int nb, int* __restrict__ offn){
  int lane = threadIdx.x;
  int v = (lane<nb)?bsum[lane]:0;
  int x = v;
  #pragma unroll
  for (int s=1;s<64;s<<=1){ int t2=__shfl_up(x,s); if (lane>=s) x+=t2; }
  if (lane<nb) bsum[lane] = x - v;
  if (lane==63) *offn = x;
}

__global__ __launch_bounds__(1024) void scan3_k(int* __restrict__ off,
                                                const int* __restrict__ bsum, int n){
  int i = blockIdx.x*1024 + threadIdx.x;
  if (i<n) off[i] += bsum[blockIdx.x];
}

__global__ void scatter_k(const int* __restrict__ src, const int* __restrict__ dst,
                          const int* __restrict__ off, int* __restrict__ cur,
                          int* __restrict__ sorted, int E){
  int e=blockIdx.x*blockDim.x+threadIdx.x;
  if (e<E){
    int d=dst[e];
    int pos=off[d]+atomicAdd(&cur[d],1);
    sorted[pos]=src[e];
  }
}

// -------- fused single-pass aggregate + softmax + LayerNorm --------
// alpha = exp(l)/sum(exp(l)) without seg-max: logits are O(+-4), exp is safe.
// den is identical on all 8 lanes of a head -> no cross-lane reduce needed.
__global__ __launch_bounds__(256) void agg2_k(const unsigned short* __restrict__ xlb,
    const float* __restrict__ a_src, const float* __restrict__ a_dst,
    const int* __restrict__ off, const int* __restrict__ sorted,
    const float* __restrict__ bias, const float* __restrict__ gamma,
    const float* __restrict__ beta, float* __restrict__ out, int n){
  int node = blockIdx.x*4 + (threadIdx.x>>6);
  int lane = threadIdx.x & 63;
  if (node >= n) return;
  int h = lane >> 3;
  float myadst = a_dst[(size_t)node*8+h];
  int s0=off[node], d=off[node+1]-s0;

  // self loop
  float wgt = __expf(lrelu(a_src[(size_t)node*8+h]+myadst));
  float den = wgt;
  ushort4 u0 = *(const ushort4*)(xlb + (size_t)node*256 + lane*4);
  float ax=wgt*b2f(u0.x), ay=wgt*b2f(u0.y), az=wgt*b2f(u0.z), aw=wgt*b2f(u0.w);

  int i=0;
  for (; i+4<=d; i+=4){
    int s1 = sorted[s0+i];
    int s2 = sorted[s0+i+1];
    int s3 = sorted[s0+i+2];
    int s4 = sorted[s0+i+3];
    float w1 = __expf(lrelu(a_src[(size_t)s1*8+h]+myadst));
    float w2 = __expf(lrelu(a_src[(size_t)s2*8+h]+myadst));
    float w3 = __expf(lrelu(a_src[(size_t)s3*8+h]+myadst));
    float w4 = __expf(lrelu(a_src[(size_t)s4*8+h]+myadst));
    ushort4 u1 = *(const ushort4*)(xlb + (size_t)s1*256 + lane*4);
    ushort4 u2 = *(const ushort4*)(xlb + (size_t)s2*256 + lane*4);
    ushort4 u3 = *(const ushort4*)(xlb + (size_t)s3*256 + lane*4);
    ushort4 u4 = *(const ushort4*)(xlb + (size_t)s4*256 + lane*4);
    den += w1 + w2 + w3 + w4;
    ax += w1*b2f(u1.x) + w2*b2f(u2.x) + w3*b2f(u3.x) + w4*b2f(u4.x);
    ay += w1*b2f(u1.y) + w2*b2f(u2.y) + w3*b2f(u3.y) + w4*b2f(u4.y);
    az += w1*b2f(u1.z) + w2*b2f(u2.z) + w3*b2f(u3.z) + w4*b2f(u4.z);
    aw += w1*b2f(u1.w) + w2*b2f(u2.w) + w3*b2f(u3.w) + w4*b2f(u4.w);
  }
  for (; i<d; i++){
    int s1 = sorted[s0+i];
    float w1 = __expf(lrelu(a_src[(size_t)s1*8+h]+myadst));
    ushort4 u1 = *(const ushort4*)(xlb + (size_t)s1*256 + lane*4);
    den += w1;
    ax += w1*b2f(u1.x); ay += w1*b2f(u1.y); az += w1*b2f(u1.z); aw += w1*b2f(u1.w);
  }

  float rd = 1.0f/den;
  float4 b4 = *(const float4*)(bias + lane*4);
  float4 o = {ax*rd+b4.x, ay*rd+b4.y, az*rd+b4.z, aw*rd+b4.w};

  // LayerNorm over 256 features (cross-wave reduce)
  float sum = o.x+o.y+o.z+o.w;
  float ssq = o.x*o.x+o.y*o.y+o.z*o.z+o.w*o.w;
  #pragma unroll
  for (int s=1;s<64;s<<=1){ sum += __shfl_xor(sum,s); ssq += __shfl_xor(ssq,s); }
  float mean = sum*(1.0f/256.0f);
  float var  = ssq*(1.0f/256.0f) - mean*mean;
  float rstd = rsqrtf(var + LNEPS);
  float4 g  = *(const float4*)(gamma + lane*4);
  float4 be = *(const float4*)(beta + lane*4);
  o.x = (o.x-mean)*rstd*g.x+be.x;
  o.y = (o.y-mean)*rstd*g.y+be.y;
  o.z = (o.z-mean)*rstd*g.z+be.z;
  o.w = (o.w-mean)*rstd*g.w+be.w;
  *(float4*)(out + (size_t)node*256 + lane*4) = o;
}

extern "C" void kernel_launch(void* const* d_in, const int* in_sizes, int n_in,
                              void* d_out, int out_size, void* d_ws, size_t ws_size,
                              hipStream_t stream){
  const float* x       = (const float*)d_in[0];
  const int*   ei      = (const int*)  d_in[1];
  const float* W       = (const float*)d_in[2];
  const float* att_src = (const float*)d_in[3];
  const float* att_dst = (const float*)d_in[4];
  const float* bias    = (const float*)d_in[5];
  const float* gamma   = (const float*)d_in[6];
  const float* beta    = (const float*)d_in[7];
  float* out = (float*)d_out;

  int N = in_sizes[0]/256;
  int E = in_sizes[1]/2;
  const int* srcp = ei;
  const int* dstp = ei + E;

  unsigned short* xlb = (unsigned short*)d_ws;               // N*256 bf16
  float* a_src = (float*)(xlb + (size_t)N*256);
  float* a_dst = a_src + (size_t)N*8;
  int*   deg   = (int*)(a_dst + (size_t)N*8);
  int*   off   = deg + N;
  int*   cur   = off + N + 1;
  int*   sorted= cur + N;
  int*   bsum  = sorted + E;
  unsigned short* WT = (unsigned short*)(bsum + 1024);

  hipMemsetAsync(deg, 0, (size_t)N*sizeof(int), stream);
  hipMemsetAsync(cur, 0, (size_t)N*sizeof(int), stream);

  int nb = (N + 1023)/1024;

  wt_k<<<256, 256, 0, stream>>>(W, WT);
  mfma_gemm_k<<<(N+63)/64, 256, 0, stream>>>(x, WT, xlb, att_src, att_dst, a_src, a_dst, N);
  deg_k<<<(E+255)/256, 256, 0, stream>>>(dstp, deg, E);
  scan1_k<<<nb, 1024, 0, stream>>>(deg, off, bsum, N);
  scan2_k<<<1, 64, 0, stream>>>(bsum, nb, off + N);
  scan3_k<<<nb, 1024, 0, stream>>>(off, bsum, N);
  scatter_k<<<(E+255)/256, 256, 0, stream>>>(srcp, dstp, off, cur, sorted, E);
  agg2_k<<<(N+3)/4, 256, 0, stream>>>(xlb, a_src, a_dst, off, sorted, bias, gamma, beta, out, N);
}

// Round 4
// 214.318 us; speedup vs baseline: 1.8863x; 1.2023x over previous
//
#include <hip/hip_runtime.h>
#include <math.h>

#define NEG 0.2f
#define LNEPS 1e-5f

typedef __attribute__((ext_vector_type(8))) short bf16x8;
typedef __attribute__((ext_vector_type(4))) float f32x4;

__device__ __forceinline__ float lrelu(float x){ return x > 0.f ? x : NEG*x; }

// f32 -> bf16 (round to nearest even), as raw short
__device__ __forceinline__ short f2b(float f){
  unsigned u = __float_as_uint(f);
  unsigned r = u + 0x7fffu + ((u >> 16) & 1u);
  return (short)(r >> 16);
}
__device__ __forceinline__ float b2f(unsigned short u){
  return __uint_as_float(((unsigned)u) << 16);
}

// -------- W transpose + bf16 convert: WT[c][k] = bf16(W[k][c]) --------
__global__ __launch_bounds__(256) void wt_k(const float* __restrict__ W,
                                            unsigned short* __restrict__ WT){
  int idx = blockIdx.x*256 + threadIdx.x;   // 65536 elements
  int k = idx >> 8, c = idx & 255;
  WT[c*256 + k] = (unsigned short)f2b(W[idx]);
}

// -------- MFMA GEMM + fused att half-logits, B-in-registers --------
// Wave w owns cols w*64..w*64+63 (heads 2w, 2w+1). B frags loaded once
// (128 VGPRs), then grid-stride over 16-row A tiles with half-tile prefetch.
__device__ __forceinline__ void load_half(float4 nx[8], const float* p){
  #pragma unroll
  for (int s=0;s<4;s++){
    nx[2*s]   = *(const float4*)(p + s*32);
    nx[2*s+1] = *(const float4*)(p + s*32 + 4);
  }
}
__device__ __forceinline__ void cvt_half(bf16x8 af[4], const float4 nx[8]){
  #pragma unroll
  for (int s=0;s<4;s++){
    af[s][0]=f2b(nx[2*s].x);   af[s][1]=f2b(nx[2*s].y);
    af[s][2]=f2b(nx[2*s].z);   af[s][3]=f2b(nx[2*s].w);
    af[s][4]=f2b(nx[2*s+1].x); af[s][5]=f2b(nx[2*s+1].y);
    af[s][6]=f2b(nx[2*s+1].z); af[s][7]=f2b(nx[2*s+1].w);
  }
}

__global__ __launch_bounds__(256, 2) void mfma_gemm_k(const float* __restrict__ A,
    const unsigned short* __restrict__ WT, unsigned short* __restrict__ Cb,
    const float* __restrict__ att_src, const float* __restrict__ att_dst,
    float* __restrict__ a_src, float* __restrict__ a_dst, int M, int nTiles){
  int w   = threadIdx.x >> 6;
  int l   = threadIdx.x & 63;
  int l15 = l & 15;
  int kg  = l >> 4;
  int colbase = w*64;

  // B fragments: bfr[j][ks] for col = colbase + j*16 + l15, k = ks*32+kg*8+[0..7]
  bf16x8 bfr[4][8];
  #pragma unroll
  for (int j=0;j<4;j++){
    const unsigned short* bp = WT + (size_t)(colbase + j*16 + l15)*256 + kg*8;
    #pragma unroll
    for (int ks=0;ks<8;ks++) bfr[j][ks] = *(const bf16x8*)(bp + ks*32);
  }
  float as_r[4], ad_r[4];
  #pragma unroll
  for (int j=0;j<4;j++){
    as_r[j] = att_src[colbase + j*16 + l15];
    ad_r[j] = att_dst[colbase + j*16 + l15];
  }

  int t = blockIdx.x;
  if (t >= nTiles) return;
  int row0 = t*16 + l15;
  const float* ap = A + (size_t)(row0 < M ? row0 : M-1)*256 + kg*8;
  float4 nx[8];
  load_half(nx, ap);                       // tile t, half 0

  while (t < nTiles){
    f32x4 acc[4];
    #pragma unroll
    for (int j=0;j<4;j++) acc[j] = (f32x4){0.f,0.f,0.f,0.f};
    bf16x8 af[4];

    cvt_half(af, nx);                      // half 0 ready
    load_half(nx, ap + 128);               // issue half 1
    #pragma unroll
    for (int s=0;s<4;s++)
      #pragma unroll
      for (int j=0;j<4;j++)
        acc[j] = __builtin_amdgcn_mfma_f32_16x16x32_bf16(af[s], bfr[j][s], acc[j], 0, 0, 0);

    int tn = t + gridDim.x;
    int rown = tn < nTiles ? tn*16 + l15 : row0;
    const float* apn = A + (size_t)(rown < M ? rown : M-1)*256 + kg*8;

    cvt_half(af, nx);                      // half 1 ready
    load_half(nx, apn);                    // issue next tile half 0
    #pragma unroll
    for (int s=0;s<4;s++)
      #pragma unroll
      for (int j=0;j<4;j++)
        acc[j] = __builtin_amdgcn_mfma_f32_16x16x32_bf16(af[s], bfr[j][4+s], acc[j], 0, 0, 0);

    // ---- epilogue: D layout col=l15, row=kg*4+reg ----
    int orow_base = t*16 + kg*4;
    #pragma unroll
    for (int j=0;j<4;j++)
      #pragma unroll
      for (int rr=0;rr<4;rr++){
        int orow = orow_base + rr;
        if (orow < M) Cb[(size_t)orow*256 + colbase + j*16 + l15] = (unsigned short)f2b(acc[j][rr]);
      }
    #pragma unroll
    for (int rr=0;rr<4;rr++){
      float p0s = acc[0][rr]*as_r[0] + acc[1][rr]*as_r[1];
      float p0d = acc[0][rr]*ad_r[0] + acc[1][rr]*ad_r[1];
      float p1s = acc[2][rr]*as_r[2] + acc[3][rr]*as_r[3];
      float p1d = acc[2][rr]*ad_r[2] + acc[3][rr]*ad_r[3];
      #pragma unroll
      for (int m=1;m<16;m<<=1){
        p0s += __shfl_xor(p0s,m); p0d += __shfl_xor(p0d,m);
        p1s += __shfl_xor(p1s,m); p1d += __shfl_xor(p1d,m);
      }
      int orow = orow_base + rr;
      if (l15==0 && orow < M){
        a_src[(size_t)orow*8 + 2*w]   = p0s;
        a_dst[(size_t)orow*8 + 2*w]   = p0d;
        a_src[(size_t)orow*8 + 2*w+1] = p1s;
        a_dst[(size_t)orow*8 + 2*w+1] = p1d;
      }
    }
    t = tn; row0 = rown; ap = apn;
  }
}

// -------- CSR build --------
__global__ void deg_k(const int* __restrict__ dst, int* __restrict__ deg, int E){
  int e = blockIdx.x*blockDim.x+threadIdx.x;
  if (e<E) atomicAdd(&deg[dst[e]],1);
}

// block-local exclusive scan of 1024 elements, block sum out
__global__ __launch_bounds__(1024) void scan1_k(const int* __restrict__ deg,
                                                int* __restrict__ off,
                                                int* __restrict__ bsum, int n){
  __shared__ int wsum[16];
  int tid=threadIdx.x, lane=tid&63, wid=tid>>6;
  int i = blockIdx.x*1024 + tid;
  int v = (i<n)?deg[i]:0;
  int x = v;
  #pragma unroll
  for (int s=1;s<64;s<<=1){ int t2=__shfl_up(x,s); if (lane>=s) x+=t2; }
  if (lane==63) wsum[wid]=x;
  __syncthreads();
  if (tid<16){
    int y=wsum[tid];
    #pragma unroll
    for (int s=1;s<16;s<<=1){ int t2=__shfl_up(y,s); if (tid>=s) y+=t2; }
    wsum[tid]=y;
  }
  __syncthreads();
  int prefix=(wid? wsum[wid-1]:0);
  if (i<n) off[i]=prefix + x - v;
  if (tid==0) bsum[blockIdx.x]=wsum[15];
}

// exclusive scan of up to 64 block sums (single wave)
__global__ void scan2_k(int* __restrict__ bsum, int nb, int* __restrict__ offn){
  int lane = threadIdx.x;
  int v = (lane<nb)?bsum[lane]:0;
  int x = v;
  #pragma unroll
  for (int s=1;s<64;s<<=1){ int t2=__shfl_up(x,s); if (lane>=s) x+=t2; }
  if (lane<nb) bsum[lane] = x - v;
  if (lane==63) *offn = x;
}

__global__ __launch_bounds__(1024) void scan3_k(int* __restrict__ off,
                                                const int* __restrict__ bsum, int n){
  int i = blockIdx.x*1024 + threadIdx.x;
  if (i<n) off[i] += bsum[blockIdx.x];
}

__global__ void scatter_k(const int* __restrict__ src, const int* __restrict__ dst,
                          const int* __restrict__ off, int* __restrict__ cur,
                          int* __restrict__ sorted, int E){
  int e=blockIdx.x*blockDim.x+threadIdx.x;
  if (e<E){
    int d=dst[e];
    int pos=off[d]+atomicAdd(&cur[d],1);
    sorted[pos]=src[e];
  }
}

// -------- fused single-pass aggregate + softmax + LayerNorm --------
__global__ __launch_bounds__(256) void agg2_k(const unsigned short* __restrict__ xlb,
    const float* __restrict__ a_src, const float* __restrict__ a_dst,
    const int* __restrict__ off, const int* __restrict__ sorted,
    const float* __restrict__ bias, const float* __restrict__ gamma,
    const float* __restrict__ beta, float* __restrict__ out, int n){
  int node = blockIdx.x*4 + (threadIdx.x>>6);
  int lane = threadIdx.x & 63;
  if (node >= n) return;
  int h = lane >> 3;
  float myadst = a_dst[(size_t)node*8+h];
  int s0=off[node], d=off[node+1]-s0;

  // self loop
  float wgt = __expf(lrelu(a_src[(size_t)node*8+h]+myadst));
  float den = wgt;
  ushort4 u0 = *(const ushort4*)(xlb + (size_t)node*256 + lane*4);
  float ax=wgt*b2f(u0.x), ay=wgt*b2f(u0.y), az=wgt*b2f(u0.z), aw=wgt*b2f(u0.w);

  int i=0;
  for (; i+4<=d; i+=4){
    int s1 = sorted[s0+i];
    int s2 = sorted[s0+i+1];
    int s3 = sorted[s0+i+2];
    int s4 = sorted[s0+i+3];
    float w1 = __expf(lrelu(a_src[(size_t)s1*8+h]+myadst));
    float w2 = __expf(lrelu(a_src[(size_t)s2*8+h]+myadst));
    float w3 = __expf(lrelu(a_src[(size_t)s3*8+h]+myadst));
    float w4 = __expf(lrelu(a_src[(size_t)s4*8+h]+myadst));
    ushort4 u1 = *(const ushort4*)(xlb + (size_t)s1*256 + lane*4);
    ushort4 u2 = *(const ushort4*)(xlb + (size_t)s2*256 + lane*4);
    ushort4 u3 = *(const ushort4*)(xlb + (size_t)s3*256 + lane*4);
    ushort4 u4 = *(const ushort4*)(xlb + (size_t)s4*256 + lane*4);
    den += w1 + w2 + w3 + w4;
    ax += w1*b2f(u1.x) + w2*b2f(u2.x) + w3*b2f(u3.x) + w4*b2f(u4.x);
    ay += w1*b2f(u1.y) + w2*b2f(u2.y) + w3*b2f(u3.y) + w4*b2f(u4.y);
    az += w1*b2f(u1.z) + w2*b2f(u2.z) + w3*b2f(u3.z) + w4*b2f(u4.z);
    aw += w1*b2f(u1.w) + w2*b2f(u2.w) + w3*b2f(u3.w) + w4*b2f(u4.w);
  }
  for (; i<d; i++){
    int s1 = sorted[s0+i];
    float w1 = __expf(lrelu(a_src[(size_t)s1*8+h]+myadst));
    ushort4 u1 = *(const ushort4*)(xlb + (size_t)s1*256 + lane*4);
    den += w1;
    ax += w1*b2f(u1.x); ay += w1*b2f(u1.y); az += w1*b2f(u1.z); aw += w1*b2f(u1.w);
  }

  float rd = 1.0f/den;
  float4 b4 = *(const float4*)(bias + lane*4);
  float4 o = {ax*rd+b4.x, ay*rd+b4.y, az*rd+b4.z, aw*rd+b4.w};

  // LayerNorm over 256 features (cross-wave reduce)
  float sum = o.x+o.y+o.z+o.w;
  float ssq = o.x*o.x+o.y*o.y+o.z*o.z+o.w*o.w;
  #pragma unroll
  for (int s=1;s<64;s<<=1){ sum += __shfl_xor(sum,s); ssq += __shfl_xor(ssq,s); }
  float mean = sum*(1.0f/256.0f);
  float var  = ssq*(1.0f/256.0f) - mean*mean;
  float rstd = rsqrtf(var + LNEPS);
  float4 g  = *(const float4*)(gamma + lane*4);
  float4 be = *(const float4*)(beta + lane*4);
  o.x = (o.x-mean)*rstd*g.x+be.x;
  o.y = (o.y-mean)*rstd*g.y+be.y;
  o.z = (o.z-mean)*rstd*g.z+be.z;
  o.w = (o.w-mean)*rstd*g.w+be.w;
  *(float4*)(out + (size_t)node*256 + lane*4) = o;
}

extern "C" void kernel_launch(void* const* d_in, const int* in_sizes, int n_in,
                              void* d_out, int out_size, void* d_ws, size_t ws_size,
                              hipStream_t stream){
  const float* x       = (const float*)d_in[0];
  const int*   ei      = (const int*)  d_in[1];
  const float* W       = (const float*)d_in[2];
  const float* att_src = (const float*)d_in[3];
  const float* att_dst = (const float*)d_in[4];
  const float* bias    = (const float*)d_in[5];
  const float* gamma   = (const float*)d_in[6];
  const float* beta    = (const float*)d_in[7];
  float* out = (float*)d_out;

  int N = in_sizes[0]/256;
  int E = in_sizes[1]/2;
  const int* srcp = ei;
  const int* dstp = ei + E;

  unsigned short* xlb = (unsigned short*)d_ws;               // N*256 bf16
  float* a_src = (float*)(xlb + (size_t)N*256);
  float* a_dst = a_src + (size_t)N*8;
  int*   deg   = (int*)(a_dst + (size_t)N*8);
  int*   off   = deg + N;
  int*   cur   = off + N + 1;
  int*   sorted= cur + N;
  int*   bsum  = sorted + E;
  unsigned short* WT = (unsigned short*)(bsum + 1024);

  hipMemsetAsync(deg, 0, (size_t)N*sizeof(int), stream);
  hipMemsetAsync(cur, 0, (size_t)N*sizeof(int), stream);

  int nb = (N + 1023)/1024;
  int nTiles = (N + 15)/16;

  wt_k<<<256, 256, 0, stream>>>(W, WT);
  mfma_gemm_k<<<512, 256, 0, stream>>>(x, WT, xlb, att_src, att_dst, a_src, a_dst, N, nTiles);
  deg_k<<<(E+255)/256, 256, 0, stream>>>(dstp, deg, E);
  scan1_k<<<nb, 1024, 0, stream>>>(deg, off, bsum, N);
  scan2_k<<<1, 64, 0, stream>>>(bsum, nb, off + N);
  scan3_k<<<nb, 1024, 0, stream>>>(off, bsum, N);
  scatter_k<<<(E+255)/256, 256, 0, stream>>>(srcp, dstp, off, cur, sorted, E);
  agg2_k<<<(N+3)/4, 256, 0, stream>>>(xlb, a_src, a_dst, off, sorted, bias, gamma, beta, out, N);
}